// Round 1
// 917.300 us; speedup vs baseline: 1.1194x; 1.1194x over previous
//
#include <hip/hip_runtime.h>
#include <math.h>

namespace {

constexpr int kL  = 1024;
constexpr int kD  = 1024;
constexpr int kB  = 4;
constexpr int kH  = 16;
constexpr int kDK = 64;
constexpr int kHID = 4096;

typedef unsigned short ushort_t;
typedef short  s16x8 __attribute__((ext_vector_type(8)));   // 8 bf16 (4 VGPRs) MFMA frag
typedef float  f32x4 __attribute__((ext_vector_type(4)));
typedef unsigned short u16x4 __attribute__((ext_vector_type(4)));

// fp32 -> bf16 round-to-nearest-even
__device__ __forceinline__ ushort_t f2bf(float f) {
    unsigned u = __float_as_uint(f);
    unsigned r = u + 0x7fffu + ((u >> 16) & 1u);
    return (ushort_t)(r >> 16);
}

// async global->LDS, 16B per lane. LDS dest = wave-uniform base + lane*16.
__device__ __forceinline__ void gld16(const void* g, void* l) {
    __builtin_amdgcn_global_load_lds((__attribute__((address_space(1))) void*)(g),
                                     (__attribute__((address_space(3))) void*)(l),
                                     16, 0, 0);
}

__device__ __forceinline__ float wred_sum(float v) {
    #pragma unroll
    for (int o = 32; o > 0; o >>= 1) v += __shfl_xor(v, o, 64);
    return v;
}

// out = z * (g * LN(x) + b). Writes bf16 always, fp32 optionally.
__global__ __launch_bounds__(256) void sln_kernel(
    const float* __restrict__ x, const float* __restrict__ z,
    const float* __restrict__ lnw, const float* __restrict__ lnb,
    const float* __restrict__ g, const float* __restrict__ bt,
    float* __restrict__ outf, ushort_t* __restrict__ outb)
{
    const int row = blockIdx.x;
    const int tid = threadIdx.x;
    const size_t base = (size_t)row * kD;
    float4 xv = ((const float4*)(x + base))[tid];
    float s  = xv.x + xv.y + xv.z + xv.w;
    float sq = xv.x * xv.x + xv.y * xv.y + xv.z * xv.z + xv.w * xv.w;
    __shared__ float r1[4], r2[4];
    float ws = wred_sum(s), wq = wred_sum(sq);
    int lane = tid & 63, wid = tid >> 6;
    if (lane == 0) { r1[wid] = ws; r2[wid] = wq; }
    __syncthreads();
    float st = r1[0] + r1[1] + r1[2] + r1[3];
    float qt = r2[0] + r2[1] + r2[2] + r2[3];
    float mean = st * (1.0f / kD);
    float var  = qt * (1.0f / kD) - mean * mean;
    float rs = rsqrtf(var + 1e-5f);
    float gv = g[0], bv = bt[0];
    float4 zv = ((const float4*)(z + base))[tid];
    float4 wv = ((const float4*)lnw)[tid];
    float4 lb = ((const float4*)lnb)[tid];
    float4 o;
    o.x = zv.x * (gv * ((xv.x - mean) * rs * wv.x + lb.x) + bv);
    o.y = zv.y * (gv * ((xv.y - mean) * rs * wv.y + lb.y) + bv);
    o.z = zv.z * (gv * ((xv.z - mean) * rs * wv.z + lb.z) + bv);
    o.w = zv.w * (gv * ((xv.w - mean) * rs * wv.w + lb.w) + bv);
    if (outf) ((float4*)(outf + base))[tid] = o;
    u16x4 ob; ob[0] = f2bf(o.x); ob[1] = f2bf(o.y); ob[2] = f2bf(o.z); ob[3] = f2bf(o.w);
    ((u16x4*)(outb + base))[tid] = ob;
}

// elementwise fp32 -> bf16, one float4 per thread
__global__ __launch_bounds__(256) void cvt_bf16(
    const float* __restrict__ x, ushort_t* __restrict__ y)
{
    int i = blockIdx.x * 256 + threadIdx.x;
    f32x4 v = ((const f32x4*)x)[i];
    u16x4 o; o[0] = f2bf(v[0]); o[1] = f2bf(v[1]); o[2] = f2bf(v[2]); o[3] = f2bf(v[3]);
    ((u16x4*)y)[i] = o;
}

// transpose + convert: src fp32 [R][C] -> dst bf16 [C][R]
__global__ __launch_bounds__(256) void twcvt(
    const float* __restrict__ src, ushort_t* __restrict__ dst, int R, int C)
{
    __shared__ float t[32][33];
    int c0 = blockIdx.x * 32, r0 = blockIdx.y * 32;
    int tx = threadIdx.x & 31, ty = threadIdx.x >> 5;
    #pragma unroll
    for (int i = 0; i < 4; i++) {
        int r = ty + i * 8;
        t[r][tx] = src[(size_t)(r0 + r) * C + c0 + tx];
    }
    __syncthreads();
    #pragma unroll
    for (int i = 0; i < 4; i++) {
        int c = ty + i * 8;
        dst[(size_t)(c0 + c) * R + r0 + tx] = f2bf(t[tx][c]);
    }
}

// vh bf16 [b][j][h*64+d] -> vhT bf16 [p=h*4+b][d][j]
__global__ __launch_bounds__(256) void vtrans(
    const ushort_t* __restrict__ vh, ushort_t* __restrict__ vhT)
{
    __shared__ ushort_t t[32][33];
    int p = blockIdx.z, b = p & 3, h = p >> 2;
    int j0 = blockIdx.x * 32, d0 = blockIdx.y * 32;
    int tx = threadIdx.x & 31, ty = threadIdx.x >> 5;
    const ushort_t* src = vh + (size_t)b * (kL * kD) + h * kDK;
    #pragma unroll
    for (int i = 0; i < 4; i++) {
        int j = ty + i * 8;
        t[j][tx] = src[(size_t)(j0 + j) * kD + d0 + tx];
    }
    __syncthreads();
    ushort_t* dst = vhT + (size_t)p * (kDK * kL);
    #pragma unroll
    for (int i = 0; i < 4; i++) {
        int d = ty + i * 8;
        dst[(size_t)(d0 + d) * kL + j0 + tx] = t[tx][d];
    }
}

// MFMA GEMM: C = scale*(A @ Bt^T) (+bias)(gelu)(+res). A[M][K], Bt[N][K] bf16.
// 128x128 tile, BK=32, 256 thr (4 waves, each 64x64). m97 structure.
// flags: 1 = gelu, 2 = bf16 output.
// mode 2 = QKV batch: z strides A += z*4096*1024, Bt += z*1024*1024,
//          C(bf16) += z*4096*1024, bias selected from {bias,bias1,bias2}.
__global__ __launch_bounds__(256) void mgemm(
    const ushort_t* __restrict__ A, int lda,
    const ushort_t* __restrict__ Bt, int ldb,
    void* __restrict__ Cv, int ldc, int K,
    const float* __restrict__ bias, const float* __restrict__ res,
    float scale, int flags, int mode,
    const float* __restrict__ bias1, const float* __restrict__ bias2)
{
    __shared__ __align__(16) ushort_t As[128 * 32];
    __shared__ __align__(16) ushort_t Bs[128 * 32];
    float*    Cf = (float*)Cv;
    ushort_t* Cb = (ushort_t*)Cv;
    if (mode == 2) {
        int z = blockIdx.z;
        A  += (size_t)z * (4096u * 1024u);
        Bt += (size_t)z * (1024u * 1024u);
        Cb += (size_t)z * (4096u * 1024u);
        if (z == 1) bias = bias1;
        else if (z == 2) bias = bias2;
    }
    const int tid = threadIdx.x;
    const int lane = tid & 63, w = tid >> 6;
    const int m0 = blockIdx.y * 128, n0 = blockIdx.x * 128;
    // staging: chunk = 16B (8 bf16). chunk p: row r=p>>2, stored col = c ^ (r&3)
    const int r0 = tid >> 2;
    const int c0 = (tid & 3) ^ (r0 & 3);
    const ushort_t* Ag0 = A  + (size_t)(m0 + r0) * lda + c0 * 8;
    const ushort_t* Ag1 = Ag0 + (size_t)64 * lda;
    const ushort_t* Bg0 = Bt + (size_t)(n0 + r0) * ldb + c0 * 8;
    const ushort_t* Bg1 = Bg0 + (size_t)64 * ldb;
    char* AsW = (char*)As + w * 1024;   // wave-uniform LDS dest
    char* BsW = (char*)Bs + w * 1024;
    const int wm = (w & 1) * 64, wn = (w >> 1) * 64;
    const int fn = lane & 15, q = lane >> 4;
    int aoff[4], boff[4];
    #pragma unroll
    for (int i = 0; i < 4; i++) {
        int ra = wm + i * 16 + fn;
        aoff[i] = (ra * 4 + (q ^ (ra & 3))) * 16;
        int rb = wn + i * 16 + fn;
        boff[i] = (rb * 4 + (q ^ (rb & 3))) * 16;
    }
    f32x4 acc[4][4] = {};
    for (int k0 = 0; k0 < K; k0 += 32) {
        gld16(Ag0 + k0, AsW);
        gld16(Ag1 + k0, AsW + 4096);
        gld16(Bg0 + k0, BsW);
        gld16(Bg1 + k0, BsW + 4096);
        __syncthreads();
        s16x8 af[4], bfr[4];
        #pragma unroll
        for (int i = 0; i < 4; i++) {
            af[i]  = *(const s16x8*)((const char*)As + aoff[i]);
            bfr[i] = *(const s16x8*)((const char*)Bs + boff[i]);
        }
        #pragma unroll
        for (int mi = 0; mi < 4; mi++)
            #pragma unroll
            for (int ni = 0; ni < 4; ni++)
                acc[mi][ni] = __builtin_amdgcn_mfma_f32_16x16x32_bf16(
                    af[mi], bfr[ni], acc[mi][ni], 0, 0, 0);
        __syncthreads();
    }
    #pragma unroll
    for (int mi = 0; mi < 4; mi++) {
        #pragma unroll
        for (int ni = 0; ni < 4; ni++) {
            #pragma unroll
            for (int r = 0; r < 4; r++) {
                int gm = m0 + wm + mi * 16 + q * 4 + r;   // C/D row = quad*4+reg
                int gn = n0 + wn + ni * 16 + fn;          // C/D col = lane&15
                float v = acc[mi][ni][r] * scale;
                if (bias) v += bias[gn];
                if (flags & 1) v = 0.5f * v * (1.0f + erff(v * 0.70710678118654752f));
                if (res) v += res[(size_t)gm * ldc + gn];
                if (flags & 2) Cb[(size_t)gm * ldc + gn] = f2bf(v);
                else           Cf[(size_t)gm * ldc + gn] = v;
            }
        }
    }
}

// Fused attention: per block = one (b,h) pair p and a 32-row Q-tile.
// 8 waves; wave w owns S cols [w*128, w*128+128).
// Phase 1: S = (Q @ K^T)/8 in accumulators; block-wide row softmax via
//   shuffle + LDS; write normalized P (fp32) to attn output.
// Phase 2: re-read own P tile (L2-hot; __syncthreads drains vmcnt so the
//   writes are in L2), convert to bf16 A-frags, ctx_partial = P_w @ V_w;
//   cross-wave reduce in LDS; write ctx bf16.
__global__ __launch_bounds__(512) void fused_attn(
    const ushort_t* __restrict__ qh, const ushort_t* __restrict__ kh,
    const ushort_t* __restrict__ vhT, float* __restrict__ attn,
    ushort_t* __restrict__ ctx)
{
    __shared__ float redm[8][32];
    __shared__ float reds[8][32];
    __shared__ float cred[4][2048];   // 32 KB: ctx partial reduce
    const int p = blockIdx.y, b = p & 3, h = p >> 2;
    const int m0 = blockIdx.x * 32;
    const int tid = threadIdx.x;
    const int lane = tid & 63, w = tid >> 6;
    const int fn = lane & 15, q = lane >> 4;
    const ushort_t* Qb = qh + (size_t)b * (kL * kD) + h * 64;
    const ushort_t* Kb = kh + (size_t)b * (kL * kD) + h * 64;
    float* Pp = attn + (size_t)p * kL * kL;

    // ---- Phase 1: S = Q K^T * 1/8 ----
    f32x4 acc[2][8] = {};
    #pragma unroll
    for (int kk = 0; kk < 2; kk++) {
        s16x8 aq[2], bq[8];
        #pragma unroll
        for (int mi = 0; mi < 2; mi++)
            aq[mi] = *(const s16x8*)(Qb + (size_t)(m0 + mi * 16 + fn) * kD + kk * 32 + q * 8);
        #pragma unroll
        for (int ni = 0; ni < 8; ni++)
            bq[ni] = *(const s16x8*)(Kb + (size_t)(w * 128 + ni * 16 + fn) * kD + kk * 32 + q * 8);
        #pragma unroll
        for (int mi = 0; mi < 2; mi++)
            #pragma unroll
            for (int ni = 0; ni < 8; ni++)
                acc[mi][ni] = __builtin_amdgcn_mfma_f32_16x16x32_bf16(
                    aq[mi], bq[ni], acc[mi][ni], 0, 0, 0);
    }

    // ---- softmax: scale, wave-local row max over 128 cols ----
    float mloc[2][4];
    #pragma unroll
    for (int mi = 0; mi < 2; mi++) {
        #pragma unroll
        for (int r = 0; r < 4; r++) {
            float m = -3.0e38f;
            #pragma unroll
            for (int ni = 0; ni < 8; ni++) {
                acc[mi][ni][r] *= 0.125f;
                m = fmaxf(m, acc[mi][ni][r]);
            }
            mloc[mi][r] = m;
        }
    }
    #pragma unroll
    for (int o = 1; o < 16; o <<= 1) {
        #pragma unroll
        for (int mi = 0; mi < 2; mi++)
            #pragma unroll
            for (int r = 0; r < 4; r++)
                mloc[mi][r] = fmaxf(mloc[mi][r], __shfl_xor(mloc[mi][r], o, 64));
    }
    if (fn == 0) {
        #pragma unroll
        for (int mi = 0; mi < 2; mi++)
            #pragma unroll
            for (int r = 0; r < 4; r++)
                redm[w][mi * 16 + q * 4 + r] = mloc[mi][r];
    }
    __syncthreads();
    // block row max -> exp -> wave-local row sum
    #pragma unroll
    for (int mi = 0; mi < 2; mi++) {
        #pragma unroll
        for (int r = 0; r < 4; r++) {
            int row = mi * 16 + q * 4 + r;
            float m = redm[0][row];
            #pragma unroll
            for (int w2 = 1; w2 < 8; w2++) m = fmaxf(m, redm[w2][row]);
            float s = 0.f;
            #pragma unroll
            for (int ni = 0; ni < 8; ni++) {
                float e = __expf(acc[mi][ni][r] - m);
                acc[mi][ni][r] = e;
                s += e;
            }
            mloc[mi][r] = s;
        }
    }
    #pragma unroll
    for (int o = 1; o < 16; o <<= 1) {
        #pragma unroll
        for (int mi = 0; mi < 2; mi++)
            #pragma unroll
            for (int r = 0; r < 4; r++)
                mloc[mi][r] += __shfl_xor(mloc[mi][r], o, 64);
    }
    if (fn == 0) {
        #pragma unroll
        for (int mi = 0; mi < 2; mi++)
            #pragma unroll
            for (int r = 0; r < 4; r++)
                reds[w][mi * 16 + q * 4 + r] = mloc[mi][r];
    }
    __syncthreads();
    float inv[2][4];
    #pragma unroll
    for (int mi = 0; mi < 2; mi++) {
        #pragma unroll
        for (int r = 0; r < 4; r++) {
            int row = mi * 16 + q * 4 + r;
            float s = reds[0][row];
            #pragma unroll
            for (int w2 = 1; w2 < 8; w2++) s += reds[w2][row];
            inv[mi][r] = 1.0f / s;
        }
    }
    // ---- write normalized P (required output) ----
    #pragma unroll
    for (int mi = 0; mi < 2; mi++)
        #pragma unroll
        for (int ni = 0; ni < 8; ni++)
            #pragma unroll
            for (int r = 0; r < 4; r++)
                Pp[(size_t)(m0 + mi * 16 + q * 4 + r) * kL + w * 128 + ni * 16 + fn]
                    = acc[mi][ni][r] * inv[mi][r];
    __syncthreads();   // drains vmcnt(0): P writes are in L2 before re-read

    // ---- Phase 2: ctx_partial = P[:, w*128:+128] @ V[w*128:+128, :] ----
    const ushort_t* Vb = vhT + (size_t)p * (kDK * kL);
    f32x4 acc2[2][4] = {};
    #pragma unroll
    for (int kk = 0; kk < 4; kk++) {
        s16x8 pa[2];
        #pragma unroll
        for (int mi = 0; mi < 2; mi++) {
            const float* src = Pp + (size_t)(m0 + mi * 16 + fn) * kL + w * 128 + kk * 32 + q * 8;
            f32x4 v0 = *(const f32x4*)src;
            f32x4 v1 = *(const f32x4*)(src + 4);
            s16x8 t;
            t[0] = (short)f2bf(v0[0]); t[1] = (short)f2bf(v0[1]);
            t[2] = (short)f2bf(v0[2]); t[3] = (short)f2bf(v0[3]);
            t[4] = (short)f2bf(v1[0]); t[5] = (short)f2bf(v1[1]);
            t[6] = (short)f2bf(v1[2]); t[7] = (short)f2bf(v1[3]);
            pa[mi] = t;
        }
        #pragma unroll
        for (int nj = 0; nj < 4; nj++) {
            s16x8 bv = *(const s16x8*)(Vb + (size_t)(nj * 16 + fn) * kL + w * 128 + kk * 32 + q * 8);
            #pragma unroll
            for (int mi = 0; mi < 2; mi++)
                acc2[mi][nj] = __builtin_amdgcn_mfma_f32_16x16x32_bf16(
                    pa[mi], bv, acc2[mi][nj], 0, 0, 0);
        }
    }
    // ---- cross-wave reduce (8 -> 4 -> 1) ----
    if (w < 4) {
        #pragma unroll
        for (int mi = 0; mi < 2; mi++)
            #pragma unroll
            for (int nj = 0; nj < 4; nj++)
                #pragma unroll
                for (int r = 0; r < 4; r++)
                    cred[w][(mi * 16 + q * 4 + r) * 64 + nj * 16 + fn] = acc2[mi][nj][r];
    }
    __syncthreads();
    if (w >= 4) {
        #pragma unroll
        for (int mi = 0; mi < 2; mi++)
            #pragma unroll
            for (int nj = 0; nj < 4; nj++)
                #pragma unroll
                for (int r = 0; r < 4; r++)
                    cred[w - 4][(mi * 16 + q * 4 + r) * 64 + nj * 16 + fn] += acc2[mi][nj][r];
    }
    __syncthreads();
    {
        int idx0 = tid * 4;                 // 512 thr * 4 = 2048 = 32x64
        int row = idx0 >> 6, d0 = idx0 & 63;
        f32x4 s0 = *(const f32x4*)&cred[0][idx0];
        #pragma unroll
        for (int wb = 1; wb < 4; wb++) {
            f32x4 t = *(const f32x4*)&cred[wb][idx0];
            s0[0] += t[0]; s0[1] += t[1]; s0[2] += t[2]; s0[3] += t[3];
        }
        u16x4 o;
        o[0] = f2bf(s0[0]); o[1] = f2bf(s0[1]); o[2] = f2bf(s0[2]); o[3] = f2bf(s0[3]);
        *(u16x4*)(ctx + (size_t)b * (kL * kD) + (size_t)(m0 + row) * kD + h * 64 + d0) = o;
    }
}

} // namespace

extern "C" void kernel_launch(void* const* d_in, const int* in_sizes, int n_in,
                              void* d_out, int out_size, void* d_ws, size_t ws_size,
                              hipStream_t stream)
{
    (void)in_sizes; (void)n_in; (void)out_size; (void)ws_size;
    const float* q      = (const float*)d_in[0];
    const float* k      = (const float*)d_in[1];
    const float* v      = (const float*)d_in[2];
    const float* z      = (const float*)d_in[3];
    const float* wq_w   = (const float*)d_in[4];
    const float* wq_b   = (const float*)d_in[5];
    const float* wk_w   = (const float*)d_in[6];
    const float* wk_b   = (const float*)d_in[7];
    const float* wv_w   = (const float*)d_in[8];
    const float* wv_b   = (const float*)d_in[9];
    const float* fc_w   = (const float*)d_in[10];
    const float* fc_b   = (const float*)d_in[11];
    const float* mlp1_w = (const float*)d_in[12];
    const float* mlp1_b = (const float*)d_in[13];
    const float* mlp2_w = (const float*)d_in[14];
    const float* mlp2_b = (const float*)d_in[15];
    const float* ln1_w  = (const float*)d_in[16];
    const float* ln1_b  = (const float*)d_in[17];
    const float* g1     = (const float*)d_in[18];
    const float* b1     = (const float*)d_in[19];
    const float* ln2_w  = (const float*)d_in[20];
    const float* ln2_b  = (const float*)d_in[21];
    const float* g2     = (const float*)d_in[22];
    const float* b2     = (const float*)d_in[23];

    float* out0 = (float*)d_out;                          // (B,L,D)
    float* attn = (float*)d_out + (size_t)kB * kL * kD;   // (H*B,L,L)

    // workspace arena (104 MB peak, with lifetime-based overlays)
    char* arena = (char*)d_ws;
    const size_t MB = 1u << 20;
    float*    qp   = (float*)(arena);                  // [0,16M)  fp32 q' (residual)
    ushort_t* qh   = (ushort_t*)(arena + 16 * MB);     // [16,24)
    ushort_t* kh   = (ushort_t*)(arena + 24 * MB);     // [24,32)
    ushort_t* vh   = (ushort_t*)(arena + 32 * MB);     // [32,40)
    ushort_t* vhT  = (ushort_t*)(arena + 40 * MB);     // [40,48)
    ushort_t* hid  = (ushort_t*)(arena + 16 * MB);     // [16,48)  overlays qh..vhT (dead)
    ushort_t* qb   = (ushort_t*)(arena + 48 * MB);     // [48,56)
    ushort_t* kb   = (ushort_t*)(arena + 56 * MB);     // [56,64)
    float*    out1 = (float*)(arena + 48 * MB);        // [48,64)  overlays qb,kb (dead)
    ushort_t* vb   = (ushort_t*)(arena + 64 * MB);     // [64,72)
    ushort_t* ctx  = (ushort_t*)(arena + 64 * MB);     // [64,72)  overlays vb (dead)
    ushort_t* h2   = (ushort_t*)(arena + 72 * MB);     // [72,80)
    ushort_t* wqT  = (ushort_t*)(arena + 80 * MB);
    ushort_t* wkT  = (ushort_t*)(arena + 82 * MB);
    ushort_t* wvT  = (ushort_t*)(arena + 84 * MB);
    ushort_t* fcT  = (ushort_t*)(arena + 86 * MB);
    ushort_t* m1T  = (ushort_t*)(arena + 88 * MB);     // [88,96)
    ushort_t* m2T  = (ushort_t*)(arena + 96 * MB);     // [96,104)

    dim3 blk(256);
    // 0) weight transpose+convert to bf16 [out][in]
    twcvt<<<dim3(32, 32), blk, 0, stream>>>(wq_w, wqT, kD, kH * kDK);
    twcvt<<<dim3(32, 32), blk, 0, stream>>>(wk_w, wkT, kD, kH * kDK);
    twcvt<<<dim3(32, 32), blk, 0, stream>>>(wv_w, wvT, kD, kH * kDK);
    twcvt<<<dim3(32, 32), blk, 0, stream>>>(fc_w, fcT, kH * kDK, kD);
    twcvt<<<dim3(128, 32), blk, 0, stream>>>(mlp1_w, m1T, kD, kHID);
    twcvt<<<dim3(32, 128), blk, 0, stream>>>(mlp2_w, m2T, kHID, kD);
    // 0b) k, v -> bf16
    cvt_bf16<<<dim3(4096), blk, 0, stream>>>(k, kb);
    cvt_bf16<<<dim3(4096), blk, 0, stream>>>(v, vb);
    // 1) q' = SLN(q, z): fp32 (residual) + bf16 (GEMM input)
    sln_kernel<<<dim3(kB * kL), blk, 0, stream>>>(q, z, ln1_w, ln1_b, g1, b1, qp, qb);
    // 2) QKV projections -> bf16 heads, one batched launch (768 blocks = 3/CU)
    mgemm<<<dim3(8, 32, 3), blk, 0, stream>>>(qb, kD, wqT, kD, qh, kD, kD,
                                              wq_b, nullptr, 1.0f, 2, 2, wk_b, wv_b);
    // 3) V^T per head
    vtrans<<<dim3(32, 2, 64), blk, 0, stream>>>(vh, vhT);
    // 4) fused scores+softmax+PV: attn (fp32, d_out) and ctx (bf16)
    fused_attn<<<dim3(kL / 32, 64), dim3(512), 0, stream>>>(qh, kh, vhT, attn, ctx);
    // 5) out1 = ctx @ fc_w + fc_b + q'  (fp32)
    mgemm<<<dim3(8, 32, 1), blk, 0, stream>>>(ctx, kD, fcT, kD, out1, kD, kD,
                                              fc_b, qp, 1.0f, 0, 0, nullptr, nullptr);
    // 6) h2 = SLN(out1, z) -> bf16 only
    sln_kernel<<<dim3(kB * kL), blk, 0, stream>>>(out1, z, ln2_w, ln2_b, g2, b2, nullptr, h2);
    // 7) hid = gelu(h2 @ mlp1 + b) -> bf16
    mgemm<<<dim3(32, 32, 1), blk, 0, stream>>>(h2, kD, m1T, kD, hid, kHID, kD,
                                               mlp1_b, nullptr, 1.0f, 3, 0, nullptr, nullptr);
    // 8) out0 = hid @ mlp2 + b + out1 (fp32)
    mgemm<<<dim3(8, 32, 1), blk, 0, stream>>>(hid, kHID, m2T, kHID, out0, kD, kHID,
                                              mlp2_b, out1, 1.0f, 0, 0, nullptr, nullptr);
}

// Round 2
// 824.342 us; speedup vs baseline: 1.2456x; 1.1128x over previous
//
#include <hip/hip_runtime.h>
#include <math.h>

namespace {

constexpr int kL  = 1024;
constexpr int kD  = 1024;
constexpr int kB  = 4;
constexpr int kH  = 16;
constexpr int kDK = 64;
constexpr int kHID = 4096;

typedef unsigned short ushort_t;
typedef short  s16x8 __attribute__((ext_vector_type(8)));   // 8 bf16 (4 VGPRs) MFMA frag
typedef float  f32x4 __attribute__((ext_vector_type(4)));
typedef unsigned short u16x4 __attribute__((ext_vector_type(4)));

// fp32 -> bf16 round-to-nearest-even
__device__ __forceinline__ ushort_t f2bf(float f) {
    unsigned u = __float_as_uint(f);
    unsigned r = u + 0x7fffu + ((u >> 16) & 1u);
    return (ushort_t)(r >> 16);
}

// async global->LDS, 16B per lane. LDS dest = wave-uniform base + lane*16.
__device__ __forceinline__ void gld16(const void* g, void* l) {
    __builtin_amdgcn_global_load_lds((__attribute__((address_space(1))) void*)(g),
                                     (__attribute__((address_space(3))) void*)(l),
                                     16, 0, 0);
}

__device__ __forceinline__ float wred_sum(float v) {
    #pragma unroll
    for (int o = 32; o > 0; o >>= 1) v += __shfl_xor(v, o, 64);
    return v;
}

// out = z * (g * LN(x) + b). Writes bf16 always, fp32 optionally.
__global__ __launch_bounds__(256) void sln_kernel(
    const float* __restrict__ x, const float* __restrict__ z,
    const float* __restrict__ lnw, const float* __restrict__ lnb,
    const float* __restrict__ g, const float* __restrict__ bt,
    float* __restrict__ outf, ushort_t* __restrict__ outb)
{
    const int row = blockIdx.x;
    const int tid = threadIdx.x;
    const size_t base = (size_t)row * kD;
    float4 xv = ((const float4*)(x + base))[tid];
    float s  = xv.x + xv.y + xv.z + xv.w;
    float sq = xv.x * xv.x + xv.y * xv.y + xv.z * xv.z + xv.w * xv.w;
    __shared__ float r1[4], r2[4];
    float ws = wred_sum(s), wq = wred_sum(sq);
    int lane = tid & 63, wid = tid >> 6;
    if (lane == 0) { r1[wid] = ws; r2[wid] = wq; }
    __syncthreads();
    float st = r1[0] + r1[1] + r1[2] + r1[3];
    float qt = r2[0] + r2[1] + r2[2] + r2[3];
    float mean = st * (1.0f / kD);
    float var  = qt * (1.0f / kD) - mean * mean;
    float rs = rsqrtf(var + 1e-5f);
    float gv = g[0], bv = bt[0];
    float4 zv = ((const float4*)(z + base))[tid];
    float4 wv = ((const float4*)lnw)[tid];
    float4 lb = ((const float4*)lnb)[tid];
    float4 o;
    o.x = zv.x * (gv * ((xv.x - mean) * rs * wv.x + lb.x) + bv);
    o.y = zv.y * (gv * ((xv.y - mean) * rs * wv.y + lb.y) + bv);
    o.z = zv.z * (gv * ((xv.z - mean) * rs * wv.z + lb.z) + bv);
    o.w = zv.w * (gv * ((xv.w - mean) * rs * wv.w + lb.w) + bv);
    if (outf) ((float4*)(outf + base))[tid] = o;
    u16x4 ob; ob[0] = f2bf(o.x); ob[1] = f2bf(o.y); ob[2] = f2bf(o.z); ob[3] = f2bf(o.w);
    ((u16x4*)(outb + base))[tid] = ob;
}

// elementwise fp32 -> bf16, one float4 per thread
__global__ __launch_bounds__(256) void cvt_bf16(
    const float* __restrict__ x, ushort_t* __restrict__ y)
{
    int i = blockIdx.x * 256 + threadIdx.x;
    f32x4 v = ((const f32x4*)x)[i];
    u16x4 o; o[0] = f2bf(v[0]); o[1] = f2bf(v[1]); o[2] = f2bf(v[2]); o[3] = f2bf(v[3]);
    ((u16x4*)y)[i] = o;
}

// transpose + convert: src fp32 [R][C] -> dst bf16 [C][R]
__global__ __launch_bounds__(256) void twcvt(
    const float* __restrict__ src, ushort_t* __restrict__ dst, int R, int C)
{
    __shared__ float t[32][33];
    int c0 = blockIdx.x * 32, r0 = blockIdx.y * 32;
    int tx = threadIdx.x & 31, ty = threadIdx.x >> 5;
    #pragma unroll
    for (int i = 0; i < 4; i++) {
        int r = ty + i * 8;
        t[r][tx] = src[(size_t)(r0 + r) * C + c0 + tx];
    }
    __syncthreads();
    #pragma unroll
    for (int i = 0; i < 4; i++) {
        int c = ty + i * 8;
        dst[(size_t)(c0 + c) * R + r0 + tx] = f2bf(t[tx][c]);
    }
}

// vh bf16 [b][j][h*64+d] -> vhT bf16 [p=h*4+b][d][j]
__global__ __launch_bounds__(256) void vtrans(
    const ushort_t* __restrict__ vh, ushort_t* __restrict__ vhT)
{
    __shared__ ushort_t t[32][33];
    int p = blockIdx.z, b = p & 3, h = p >> 2;
    int j0 = blockIdx.x * 32, d0 = blockIdx.y * 32;
    int tx = threadIdx.x & 31, ty = threadIdx.x >> 5;
    const ushort_t* src = vh + (size_t)b * (kL * kD) + h * kDK;
    #pragma unroll
    for (int i = 0; i < 4; i++) {
        int j = ty + i * 8;
        t[j][tx] = src[(size_t)(j0 + j) * kD + d0 + tx];
    }
    __syncthreads();
    ushort_t* dst = vhT + (size_t)p * (kDK * kL);
    #pragma unroll
    for (int i = 0; i < 4; i++) {
        int d = ty + i * 8;
        dst[(size_t)(d0 + d) * kL + j0 + tx] = t[tx][d];
    }
}

// MFMA GEMM: C = scale*(A @ Bt^T) (+bias)(gelu)(+res). A[M][K], Bt[N][K] bf16.
// 128x128 tile, BK=32, 256 thr (4 waves, each 64x64). m97 structure.
// flags: 1 = gelu, 2 = bf16 output.
// mode 2 = QKV batch: z strides A += z*4096*1024, Bt += z*1024*1024,
//          C(bf16) += z*4096*1024, bias selected from {bias,bias1,bias2}.
__global__ __launch_bounds__(256) void mgemm(
    const ushort_t* __restrict__ A, int lda,
    const ushort_t* __restrict__ Bt, int ldb,
    void* __restrict__ Cv, int ldc, int K,
    const float* __restrict__ bias, const float* __restrict__ res,
    float scale, int flags, int mode,
    const float* __restrict__ bias1, const float* __restrict__ bias2)
{
    __shared__ __align__(16) ushort_t As[128 * 32];
    __shared__ __align__(16) ushort_t Bs[128 * 32];
    float*    Cf = (float*)Cv;
    ushort_t* Cb = (ushort_t*)Cv;
    if (mode == 2) {
        int z = blockIdx.z;
        A  += (size_t)z * (4096u * 1024u);
        Bt += (size_t)z * (1024u * 1024u);
        Cb += (size_t)z * (4096u * 1024u);
        if (z == 1) bias = bias1;
        else if (z == 2) bias = bias2;
    }
    const int tid = threadIdx.x;
    const int lane = tid & 63, w = tid >> 6;
    const int m0 = blockIdx.y * 128, n0 = blockIdx.x * 128;
    // staging: chunk = 16B (8 bf16). chunk p: row r=p>>2, stored col = c ^ (r&3)
    const int r0 = tid >> 2;
    const int c0 = (tid & 3) ^ (r0 & 3);
    const ushort_t* Ag0 = A  + (size_t)(m0 + r0) * lda + c0 * 8;
    const ushort_t* Ag1 = Ag0 + (size_t)64 * lda;
    const ushort_t* Bg0 = Bt + (size_t)(n0 + r0) * ldb + c0 * 8;
    const ushort_t* Bg1 = Bg0 + (size_t)64 * ldb;
    char* AsW = (char*)As + w * 1024;   // wave-uniform LDS dest
    char* BsW = (char*)Bs + w * 1024;
    const int wm = (w & 1) * 64, wn = (w >> 1) * 64;
    const int fn = lane & 15, q = lane >> 4;
    int aoff[4], boff[4];
    #pragma unroll
    for (int i = 0; i < 4; i++) {
        int ra = wm + i * 16 + fn;
        aoff[i] = (ra * 4 + (q ^ (ra & 3))) * 16;
        int rb = wn + i * 16 + fn;
        boff[i] = (rb * 4 + (q ^ (rb & 3))) * 16;
    }
    f32x4 acc[4][4] = {};
    for (int k0 = 0; k0 < K; k0 += 32) {
        gld16(Ag0 + k0, AsW);
        gld16(Ag1 + k0, AsW + 4096);
        gld16(Bg0 + k0, BsW);
        gld16(Bg1 + k0, BsW + 4096);
        __syncthreads();
        s16x8 af[4], bfr[4];
        #pragma unroll
        for (int i = 0; i < 4; i++) {
            af[i]  = *(const s16x8*)((const char*)As + aoff[i]);
            bfr[i] = *(const s16x8*)((const char*)Bs + boff[i]);
        }
        #pragma unroll
        for (int mi = 0; mi < 4; mi++)
            #pragma unroll
            for (int ni = 0; ni < 4; ni++)
                acc[mi][ni] = __builtin_amdgcn_mfma_f32_16x16x32_bf16(
                    af[mi], bfr[ni], acc[mi][ni], 0, 0, 0);
        __syncthreads();
    }
    #pragma unroll
    for (int mi = 0; mi < 4; mi++) {
        #pragma unroll
        for (int ni = 0; ni < 4; ni++) {
            #pragma unroll
            for (int r = 0; r < 4; r++) {
                int gm = m0 + wm + mi * 16 + q * 4 + r;   // C/D row = quad*4+reg
                int gn = n0 + wn + ni * 16 + fn;          // C/D col = lane&15
                float v = acc[mi][ni][r] * scale;
                if (bias) v += bias[gn];
                if (flags & 1) v = 0.5f * v * (1.0f + erff(v * 0.70710678118654752f));
                if (res) v += res[(size_t)gm * ldc + gn];
                if (flags & 2) Cb[(size_t)gm * ldc + gn] = f2bf(v);
                else           Cf[(size_t)gm * ldc + gn] = v;
            }
        }
    }
}

// Fused attention: per block = one (b,h) pair p and a 32-row Q-tile.
// 8 waves; wave w owns S cols [w*128, w*128+128).
// Phase 1: S = (Q @ K^T)/8 in accumulators; block-wide row softmax via
//   shuffle + LDS; write normalized P (fp32, nontemporal) to attn output.
// Phase 2: E (unnormalized exp, bf16) routed through a per-wave XOR-swizzled
//   LDS transpose buffer (two 64-col halves, 4 KB/wave); ctx_partial =
//   (E @ V) * inv; cross-wave reduce in LDS (overlays E buffer); write ctx.
// XCD-aware bijective block swizzle: each XCD owns 8 consecutive p values so
//   K/V (256 KB per p) stay resident in its private L2.
__global__ __launch_bounds__(512) void fused_attn(
    const ushort_t* __restrict__ qh, const ushort_t* __restrict__ kh,
    const ushort_t* __restrict__ vhT, float* __restrict__ attn,
    ushort_t* __restrict__ ctx)
{
    __shared__ __align__(16) char PlBuf[8 * 4096];   // 32 KB: per-wave E tiles / cred overlay
    __shared__ float redm[8][32];
    __shared__ float reds[8][32];
    // bijective XCD swizzle: orig p-major flat id -> XCD-contiguous
    const int orig = blockIdx.y * 32 + blockIdx.x;   // grid (32, 64), 2048 blocks
    const int nf = (orig & 7) * 256 + (orig >> 3);
    const int p = nf >> 5, b = p & 3, h = p >> 2;
    const int m0 = (nf & 31) * 32;
    const int tid = threadIdx.x;
    const int lane = tid & 63, w = tid >> 6;
    const int fn = lane & 15, q = lane >> 4;
    const ushort_t* Qb = qh + (size_t)b * (kL * kD) + h * 64;
    const ushort_t* Kb = kh + (size_t)b * (kL * kD) + h * 64;
    float* Pp = attn + (size_t)p * kL * kL;

    // ---- Phase 1: S = Q K^T * 1/8 ----
    f32x4 acc[2][8] = {};
    #pragma unroll
    for (int kk = 0; kk < 2; kk++) {
        s16x8 aq[2], bq[8];
        #pragma unroll
        for (int mi = 0; mi < 2; mi++)
            aq[mi] = *(const s16x8*)(Qb + (size_t)(m0 + mi * 16 + fn) * kD + kk * 32 + q * 8);
        #pragma unroll
        for (int ni = 0; ni < 8; ni++)
            bq[ni] = *(const s16x8*)(Kb + (size_t)(w * 128 + ni * 16 + fn) * kD + kk * 32 + q * 8);
        #pragma unroll
        for (int mi = 0; mi < 2; mi++)
            #pragma unroll
            for (int ni = 0; ni < 8; ni++)
                acc[mi][ni] = __builtin_amdgcn_mfma_f32_16x16x32_bf16(
                    aq[mi], bq[ni], acc[mi][ni], 0, 0, 0);
    }

    // ---- softmax: scale, wave-local row max over 128 cols ----
    float mloc[2][4];
    #pragma unroll
    for (int mi = 0; mi < 2; mi++) {
        #pragma unroll
        for (int r = 0; r < 4; r++) {
            float m = -3.0e38f;
            #pragma unroll
            for (int ni = 0; ni < 8; ni++) {
                acc[mi][ni][r] *= 0.125f;
                m = fmaxf(m, acc[mi][ni][r]);
            }
            mloc[mi][r] = m;
        }
    }
    #pragma unroll
    for (int o = 1; o < 16; o <<= 1) {
        #pragma unroll
        for (int mi = 0; mi < 2; mi++)
            #pragma unroll
            for (int r = 0; r < 4; r++)
                mloc[mi][r] = fmaxf(mloc[mi][r], __shfl_xor(mloc[mi][r], o, 64));
    }
    if (fn == 0) {
        #pragma unroll
        for (int mi = 0; mi < 2; mi++)
            #pragma unroll
            for (int r = 0; r < 4; r++)
                redm[w][mi * 16 + q * 4 + r] = mloc[mi][r];
    }
    __syncthreads();
    // block row max -> exp -> wave-local row sum
    #pragma unroll
    for (int mi = 0; mi < 2; mi++) {
        #pragma unroll
        for (int r = 0; r < 4; r++) {
            int row = mi * 16 + q * 4 + r;
            float m = redm[0][row];
            #pragma unroll
            for (int w2 = 1; w2 < 8; w2++) m = fmaxf(m, redm[w2][row]);
            float s = 0.f;
            #pragma unroll
            for (int ni = 0; ni < 8; ni++) {
                float e = __expf(acc[mi][ni][r] - m);
                acc[mi][ni][r] = e;
                s += e;
            }
            mloc[mi][r] = s;
        }
    }
    #pragma unroll
    for (int o = 1; o < 16; o <<= 1) {
        #pragma unroll
        for (int mi = 0; mi < 2; mi++)
            #pragma unroll
            for (int r = 0; r < 4; r++)
                mloc[mi][r] += __shfl_xor(mloc[mi][r], o, 64);
    }
    if (fn == 0) {
        #pragma unroll
        for (int mi = 0; mi < 2; mi++)
            #pragma unroll
            for (int r = 0; r < 4; r++)
                reds[w][mi * 16 + q * 4 + r] = mloc[mi][r];
    }
    __syncthreads();
    float inv[2][4];
    #pragma unroll
    for (int mi = 0; mi < 2; mi++) {
        #pragma unroll
        for (int r = 0; r < 4; r++) {
            int row = mi * 16 + q * 4 + r;
            float s = reds[0][row];
            #pragma unroll
            for (int w2 = 1; w2 < 8; w2++) s += reds[w2][row];
            inv[mi][r] = 1.0f / s;
        }
    }
    // ---- write normalized P (required output), nontemporal: never re-read ----
    #pragma unroll
    for (int mi = 0; mi < 2; mi++)
        #pragma unroll
        for (int ni = 0; ni < 8; ni++)
            #pragma unroll
            for (int r = 0; r < 4; r++)
                __builtin_nontemporal_store(
                    acc[mi][ni][r] * inv[mi][r],
                    &Pp[(size_t)(m0 + mi * 16 + q * 4 + r) * kL + w * 128 + ni * 16 + fn]);

    // ---- Phase 2: ctx_partial = (E @ V) * inv via per-wave LDS transpose ----
    // E tile 32x128 bf16 handled in two 64-col halves (4 KB/wave window).
    // LDS layout per half: byte(row, cl) = (row*128 + cl*2) ^ ((row&7)<<4).
    const ushort_t* Vb = vhT + (size_t)p * (kDK * kL);
    char* Plw = PlBuf + w * 4096;
    f32x4 acc2[2][4] = {};
    #pragma unroll
    for (int half = 0; half < 2; half++) {
        #pragma unroll
        for (int mi = 0; mi < 2; mi++)
            #pragma unroll
            for (int ni = 0; ni < 4; ni++)
                #pragma unroll
                for (int r = 0; r < 4; r++) {
                    int row = mi * 16 + q * 4 + r;
                    int cl  = ni * 16 + fn;
                    *(ushort_t*)(Plw + ((row * 128 + cl * 2) ^ ((row & 7) << 4)))
                        = f2bf(acc[mi][half * 4 + ni][r]);
                }
        // per-wave data: DS ops from one wave complete in order; no barrier needed
        #pragma unroll
        for (int kh = 0; kh < 2; kh++) {
            int kk = half * 2 + kh;
            s16x8 pa[2];
            #pragma unroll
            for (int mi = 0; mi < 2; mi++) {
                int row = mi * 16 + fn;
                pa[mi] = *(const s16x8*)(Plw +
                    ((row * 128 + (kh * 32 + q * 8) * 2) ^ ((row & 7) << 4)));
            }
            #pragma unroll
            for (int nj = 0; nj < 4; nj++) {
                s16x8 bv = *(const s16x8*)(Vb + (size_t)(nj * 16 + fn) * kL +
                                           w * 128 + kk * 32 + q * 8);
                #pragma unroll
                for (int mi = 0; mi < 2; mi++)
                    acc2[mi][nj] = __builtin_amdgcn_mfma_f32_16x16x32_bf16(
                        pa[mi], bv, acc2[mi][nj], 0, 0, 0);
            }
        }
    }
    // normalize: ctx = diag(inv) * (E @ V)
    #pragma unroll
    for (int mi = 0; mi < 2; mi++)
        #pragma unroll
        for (int nj = 0; nj < 4; nj++)
            #pragma unroll
            for (int r = 0; r < 4; r++)
                acc2[mi][nj][r] *= inv[mi][r];

    // ---- cross-wave reduce (8 -> 4 -> 1); cred overlays PlBuf ----
    __syncthreads();   // all waves done reading their E tiles
    float (*cred)[2048] = (float (*)[2048])PlBuf;   // 4 x 8 KB = 32 KB
    if (w < 4) {
        #pragma unroll
        for (int mi = 0; mi < 2; mi++)
            #pragma unroll
            for (int nj = 0; nj < 4; nj++)
                #pragma unroll
                for (int r = 0; r < 4; r++)
                    cred[w][(mi * 16 + q * 4 + r) * 64 + nj * 16 + fn] = acc2[mi][nj][r];
    }
    __syncthreads();
    if (w >= 4) {
        #pragma unroll
        for (int mi = 0; mi < 2; mi++)
            #pragma unroll
            for (int nj = 0; nj < 4; nj++)
                #pragma unroll
                for (int r = 0; r < 4; r++)
                    cred[w - 4][(mi * 16 + q * 4 + r) * 64 + nj * 16 + fn] += acc2[mi][nj][r];
    }
    __syncthreads();
    {
        int idx0 = tid * 4;                 // 512 thr * 4 = 2048 = 32x64
        int row = idx0 >> 6, d0 = idx0 & 63;
        f32x4 s0 = *(const f32x4*)&cred[0][idx0];
        #pragma unroll
        for (int wb = 1; wb < 4; wb++) {
            f32x4 t = *(const f32x4*)&cred[wb][idx0];
            s0[0] += t[0]; s0[1] += t[1]; s0[2] += t[2]; s0[3] += t[3];
        }
        u16x4 o;
        o[0] = f2bf(s0[0]); o[1] = f2bf(s0[1]); o[2] = f2bf(s0[2]); o[3] = f2bf(s0[3]);
        *(u16x4*)(ctx + (size_t)b * (kL * kD) + (size_t)(m0 + row) * kD + h * 64 + d0) = o;
    }
}

} // namespace

extern "C" void kernel_launch(void* const* d_in, const int* in_sizes, int n_in,
                              void* d_out, int out_size, void* d_ws, size_t ws_size,
                              hipStream_t stream)
{
    (void)in_sizes; (void)n_in; (void)out_size; (void)ws_size;
    const float* q      = (const float*)d_in[0];
    const float* k      = (const float*)d_in[1];
    const float* v      = (const float*)d_in[2];
    const float* z      = (const float*)d_in[3];
    const float* wq_w   = (const float*)d_in[4];
    const float* wq_b   = (const float*)d_in[5];
    const float* wk_w   = (const float*)d_in[6];
    const float* wk_b   = (const float*)d_in[7];
    const float* wv_w   = (const float*)d_in[8];
    const float* wv_b   = (const float*)d_in[9];
    const float* fc_w   = (const float*)d_in[10];
    const float* fc_b   = (const float*)d_in[11];
    const float* mlp1_w = (const float*)d_in[12];
    const float* mlp1_b = (const float*)d_in[13];
    const float* mlp2_w = (const float*)d_in[14];
    const float* mlp2_b = (const float*)d_in[15];
    const float* ln1_w  = (const float*)d_in[16];
    const float* ln1_b  = (const float*)d_in[17];
    const float* g1     = (const float*)d_in[18];
    const float* b1     = (const float*)d_in[19];
    const float* ln2_w  = (const float*)d_in[20];
    const float* ln2_b  = (const float*)d_in[21];
    const float* g2     = (const float*)d_in[22];
    const float* b2     = (const float*)d_in[23];

    float* out0 = (float*)d_out;                          // (B,L,D)
    float* attn = (float*)d_out + (size_t)kB * kL * kD;   // (H*B,L,L)

    // workspace arena (104 MB peak, with lifetime-based overlays)
    char* arena = (char*)d_ws;
    const size_t MB = 1u << 20;
    float*    qp   = (float*)(arena);                  // [0,16M)  fp32 q' (residual)
    ushort_t* qh   = (ushort_t*)(arena + 16 * MB);     // [16,24)
    ushort_t* kh   = (ushort_t*)(arena + 24 * MB);     // [24,32)
    ushort_t* vh   = (ushort_t*)(arena + 32 * MB);     // [32,40)
    ushort_t* vhT  = (ushort_t*)(arena + 40 * MB);     // [40,48)
    ushort_t* hid  = (ushort_t*)(arena + 16 * MB);     // [16,48)  overlays qh..vhT (dead)
    ushort_t* qb   = (ushort_t*)(arena + 48 * MB);     // [48,56)
    ushort_t* kb   = (ushort_t*)(arena + 56 * MB);     // [56,64)
    float*    out1 = (float*)(arena + 48 * MB);        // [48,64)  overlays qb,kb (dead)
    ushort_t* vb   = (ushort_t*)(arena + 64 * MB);     // [64,72)
    ushort_t* ctx  = (ushort_t*)(arena + 64 * MB);     // [64,72)  overlays vb (dead)
    ushort_t* h2   = (ushort_t*)(arena + 72 * MB);     // [72,80)
    ushort_t* wqT  = (ushort_t*)(arena + 80 * MB);
    ushort_t* wkT  = (ushort_t*)(arena + 82 * MB);
    ushort_t* wvT  = (ushort_t*)(arena + 84 * MB);
    ushort_t* fcT  = (ushort_t*)(arena + 86 * MB);
    ushort_t* m1T  = (ushort_t*)(arena + 88 * MB);     // [88,96)
    ushort_t* m2T  = (ushort_t*)(arena + 96 * MB);     // [96,104)

    dim3 blk(256);
    // 0) weight transpose+convert to bf16 [out][in]
    twcvt<<<dim3(32, 32), blk, 0, stream>>>(wq_w, wqT, kD, kH * kDK);
    twcvt<<<dim3(32, 32), blk, 0, stream>>>(wk_w, wkT, kD, kH * kDK);
    twcvt<<<dim3(32, 32), blk, 0, stream>>>(wv_w, wvT, kD, kH * kDK);
    twcvt<<<dim3(32, 32), blk, 0, stream>>>(fc_w, fcT, kH * kDK, kD);
    twcvt<<<dim3(128, 32), blk, 0, stream>>>(mlp1_w, m1T, kD, kHID);
    twcvt<<<dim3(32, 128), blk, 0, stream>>>(mlp2_w, m2T, kHID, kD);
    // 0b) k, v -> bf16
    cvt_bf16<<<dim3(4096), blk, 0, stream>>>(k, kb);
    cvt_bf16<<<dim3(4096), blk, 0, stream>>>(v, vb);
    // 1) q' = SLN(q, z): fp32 (residual) + bf16 (GEMM input)
    sln_kernel<<<dim3(kB * kL), blk, 0, stream>>>(q, z, ln1_w, ln1_b, g1, b1, qp, qb);
    // 2) QKV projections -> bf16 heads, one batched launch (768 blocks = 3/CU)
    mgemm<<<dim3(8, 32, 3), blk, 0, stream>>>(qb, kD, wqT, kD, qh, kD, kD,
                                              wq_b, nullptr, 1.0f, 2, 2, wk_b, wv_b);
    // 3) V^T per head
    vtrans<<<dim3(32, 2, 64), blk, 0, stream>>>(vh, vhT);
    // 4) fused scores+softmax+PV: attn (fp32, d_out) and ctx (bf16)
    fused_attn<<<dim3(kL / 32, 64), dim3(512), 0, stream>>>(qh, kh, vhT, attn, ctx);
    // 5) out1 = ctx @ fc_w + fc_b + q'  (fp32)
    mgemm<<<dim3(8, 32, 1), blk, 0, stream>>>(ctx, kD, fcT, kD, out1, kD, kD,
                                              fc_b, qp, 1.0f, 0, 0, nullptr, nullptr);
    // 6) h2 = SLN(out1, z) -> bf16 only
    sln_kernel<<<dim3(kB * kL), blk, 0, stream>>>(out1, z, ln2_w, ln2_b, g2, b2, nullptr, h2);
    // 7) hid = gelu(h2 @ mlp1 + b) -> bf16
    mgemm<<<dim3(32, 32, 1), blk, 0, stream>>>(h2, kD, m1T, kD, hid, kHID, kD,
                                               mlp1_b, nullptr, 1.0f, 3, 0, nullptr, nullptr);
    // 8) out0 = hid @ mlp2 + b + out1 (fp32)
    mgemm<<<dim3(8, 32, 1), blk, 0, stream>>>(hid, kHID, m2T, kHID, out0, kD, kHID,
                                              mlp2_b, out1, 1.0f, 0, 0, nullptr, nullptr);
}

// Round 3
// 780.573 us; speedup vs baseline: 1.3155x; 1.0561x over previous
//
#include <hip/hip_runtime.h>
#include <math.h>

namespace {

constexpr int kL  = 1024;
constexpr int kD  = 1024;
constexpr int kB  = 4;
constexpr int kH  = 16;
constexpr int kDK = 64;
constexpr int kHID = 4096;

typedef unsigned short ushort_t;
typedef short  s16x8 __attribute__((ext_vector_type(8)));   // 8 bf16 (4 VGPRs) MFMA frag
typedef float  f32x4 __attribute__((ext_vector_type(4)));
typedef unsigned short u16x4 __attribute__((ext_vector_type(4)));

// fp32 -> bf16 round-to-nearest-even
__device__ __forceinline__ ushort_t f2bf(float f) {
    unsigned u = __float_as_uint(f);
    unsigned r = u + 0x7fffu + ((u >> 16) & 1u);
    return (ushort_t)(r >> 16);
}

// async global->LDS, 16B per lane. LDS dest = wave-uniform base + lane*16.
__device__ __forceinline__ void gld16(const void* g, void* l) {
    __builtin_amdgcn_global_load_lds((__attribute__((address_space(1))) void*)(g),
                                     (__attribute__((address_space(3))) void*)(l),
                                     16, 0, 0);
}

__device__ __forceinline__ float wred_sum(float v) {
    #pragma unroll
    for (int o = 32; o > 0; o >>= 1) v += __shfl_xor(v, o, 64);
    return v;
}

// out = z * (g * LN(x) + b), where x = x1 (+ x2 partial).
// Optionally writes the summed x back (xw) and the fp32 result (outf).
__global__ __launch_bounds__(256) void sln_kernel(
    const float* __restrict__ x, const float* __restrict__ x2, float* __restrict__ xw,
    const float* __restrict__ z,
    const float* __restrict__ lnw, const float* __restrict__ lnb,
    const float* __restrict__ g, const float* __restrict__ bt,
    float* __restrict__ outf, ushort_t* __restrict__ outb)
{
    const int row = blockIdx.x;
    const int tid = threadIdx.x;
    const size_t base = (size_t)row * kD;
    float4 xv = ((const float4*)(x + base))[tid];
    if (x2) {
        float4 a = ((const float4*)(x2 + base))[tid];
        xv.x += a.x; xv.y += a.y; xv.z += a.z; xv.w += a.w;
    }
    if (xw) ((float4*)(xw + base))[tid] = xv;
    float s  = xv.x + xv.y + xv.z + xv.w;
    float sq = xv.x * xv.x + xv.y * xv.y + xv.z * xv.z + xv.w * xv.w;
    __shared__ float r1[4], r2[4];
    float ws = wred_sum(s), wq = wred_sum(sq);
    int lane = tid & 63, wid = tid >> 6;
    if (lane == 0) { r1[wid] = ws; r2[wid] = wq; }
    __syncthreads();
    float st = r1[0] + r1[1] + r1[2] + r1[3];
    float qt = r2[0] + r2[1] + r2[2] + r2[3];
    float mean = st * (1.0f / kD);
    float var  = qt * (1.0f / kD) - mean * mean;
    float rs = rsqrtf(var + 1e-5f);
    float gv = g[0], bv = bt[0];
    float4 zv = ((const float4*)(z + base))[tid];
    float4 wv = ((const float4*)lnw)[tid];
    float4 lb = ((const float4*)lnb)[tid];
    float4 o;
    o.x = zv.x * (gv * ((xv.x - mean) * rs * wv.x + lb.x) + bv);
    o.y = zv.y * (gv * ((xv.y - mean) * rs * wv.y + lb.y) + bv);
    o.z = zv.z * (gv * ((xv.z - mean) * rs * wv.z + lb.z) + bv);
    o.w = zv.w * (gv * ((xv.w - mean) * rs * wv.w + lb.w) + bv);
    if (outf) ((float4*)(outf + base))[tid] = o;
    u16x4 ob; ob[0] = f2bf(o.x); ob[1] = f2bf(o.y); ob[2] = f2bf(o.z); ob[3] = f2bf(o.w);
    ((u16x4*)(outb + base))[tid] = ob;
}

// k and v fp32 -> bf16 in one launch. blocks [0,4096) -> k, [4096,8192) -> v.
__global__ __launch_bounds__(256) void cvt2_bf16(
    const float* __restrict__ kx, const float* __restrict__ vx, ushort_t* __restrict__ kv)
{
    int b = blockIdx.x;
    bool isv = b >= 4096;
    const float* src = isv ? vx : kx;
    ushort_t* dst = kv + (isv ? (size_t)4194304 : 0);
    int i = (b & 4095) * 256 + threadIdx.x;
    f32x4 v = ((const f32x4*)src)[i];
    u16x4 o; o[0] = f2bf(v[0]); o[1] = f2bf(v[1]); o[2] = f2bf(v[2]); o[3] = f2bf(v[3]);
    ((u16x4*)dst)[i] = o;
}

// dst elementwise += src (fp32, float4 per thread)
__global__ __launch_bounds__(256) void addf4(
    float* __restrict__ dst, const float* __restrict__ src)
{
    int i = blockIdx.x * 256 + threadIdx.x;
    f32x4 d = ((const f32x4*)dst)[i];
    f32x4 s = ((const f32x4*)src)[i];
    d[0] += s[0]; d[1] += s[1]; d[2] += s[2]; d[3] += s[3];
    ((f32x4*)dst)[i] = d;
}

// transpose + convert: src fp32 [R][C] -> dst bf16 [C][R]
__global__ __launch_bounds__(256) void twcvt(
    const float* __restrict__ src, ushort_t* __restrict__ dst, int R, int C)
{
    __shared__ float t[32][33];
    int c0 = blockIdx.x * 32, r0 = blockIdx.y * 32;
    int tx = threadIdx.x & 31, ty = threadIdx.x >> 5;
    #pragma unroll
    for (int i = 0; i < 4; i++) {
        int r = ty + i * 8;
        t[r][tx] = src[(size_t)(r0 + r) * C + c0 + tx];
    }
    __syncthreads();
    #pragma unroll
    for (int i = 0; i < 4; i++) {
        int c = ty + i * 8;
        dst[(size_t)(c0 + c) * R + r0 + tx] = f2bf(t[tx][c]);
    }
}

// four 1024x1024 transposes (wq,wk,wv,fc) in one launch; dsts contiguous 2MB apart
__global__ __launch_bounds__(256) void twcvt4(
    const float* __restrict__ s0, const float* __restrict__ s1,
    const float* __restrict__ s2, const float* __restrict__ s3,
    ushort_t* __restrict__ dst)
{
    __shared__ float t[32][33];
    int zz = blockIdx.z;
    const float* src = zz == 0 ? s0 : zz == 1 ? s1 : zz == 2 ? s2 : s3;
    ushort_t* d = dst + (size_t)zz * 1048576;
    int c0 = blockIdx.x * 32, r0 = blockIdx.y * 32;
    int tx = threadIdx.x & 31, ty = threadIdx.x >> 5;
    #pragma unroll
    for (int i = 0; i < 4; i++) {
        int r = ty + i * 8;
        t[r][tx] = src[(size_t)(r0 + r) * 1024 + c0 + tx];
    }
    __syncthreads();
    #pragma unroll
    for (int i = 0; i < 4; i++) {
        int c = ty + i * 8;
        d[(size_t)(c0 + c) * 1024 + r0 + tx] = f2bf(t[tx][c]);
    }
}

// vh bf16 [b][j][h*64+d] -> vhT bf16 [p=h*4+b][d][j]
__global__ __launch_bounds__(256) void vtrans(
    const ushort_t* __restrict__ vh, ushort_t* __restrict__ vhT)
{
    __shared__ ushort_t t[32][33];
    int p = blockIdx.z, b = p & 3, h = p >> 2;
    int j0 = blockIdx.x * 32, d0 = blockIdx.y * 32;
    int tx = threadIdx.x & 31, ty = threadIdx.x >> 5;
    const ushort_t* src = vh + (size_t)b * (kL * kD) + h * kDK;
    #pragma unroll
    for (int i = 0; i < 4; i++) {
        int j = ty + i * 8;
        t[j][tx] = src[(size_t)(j0 + j) * kD + d0 + tx];
    }
    __syncthreads();
    ushort_t* dst = vhT + (size_t)p * (kDK * kL);
    #pragma unroll
    for (int i = 0; i < 4; i++) {
        int d = ty + i * 8;
        dst[(size_t)(d0 + d) * kL + j0 + tx] = t[tx][d];
    }
}

// MFMA GEMM: C = scale*(A @ Bt^T) (+bias)(gelu)(+res). A[M][K], Bt[N][K] bf16.
// 128x128 tile, BK=32, 256 thr (4 waves, each 64x64). m97 structure.
// flags: 1 = gelu, 2 = bf16 output.
// mode 2 = QKV batch: z strides A += z*4M, Bt += z*1M, C(bf16) += z*4M,
//          bias from {bias,bias1,bias2}.
// mode 3 = split-K x2: A/Bt k-offset += z*K; z==1 writes raw fp32 partial to Cv2.
// XCD-aware bijective swizzle on (bx,by): each XCD gets contiguous bx-major
// chunk so A-panels stay L2-resident (requires nwg%8==0; all our grids comply).
__global__ __launch_bounds__(256) void mgemm(
    const ushort_t* __restrict__ A, int lda,
    const ushort_t* __restrict__ Bt, int ldb,
    void* __restrict__ Cv, int ldc, int K,
    const float* __restrict__ bias, const float* __restrict__ res,
    float scale, int flags, int mode,
    const float* __restrict__ bias1, const float* __restrict__ bias2,
    void* __restrict__ Cv2)
{
    __shared__ __align__(16) ushort_t As[128 * 32];
    __shared__ __align__(16) ushort_t Bs[128 * 32];
    if (mode == 2) {
        int z = blockIdx.z;
        A  += (size_t)z * (4096u * 1024u);
        Bt += (size_t)z * (1024u * 1024u);
        Cv = (void*)((ushort_t*)Cv + (size_t)z * (4096u * 1024u));
        if (z == 1) bias = bias1;
        else if (z == 2) bias = bias2;
    } else if (mode == 3) {
        int z = blockIdx.z;
        A  += (size_t)z * K;
        Bt += (size_t)z * K;
        if (z == 1) { Cv = Cv2; bias = nullptr; res = nullptr; flags = 0; }
    }
    float*    Cf = (float*)Cv;
    ushort_t* Cb = (ushort_t*)Cv;
    // XCD swizzle (bijective, nwg%8==0)
    const int nx = gridDim.x, nwg = nx * gridDim.y;
    int f = blockIdx.y * nx + blockIdx.x;
    int rr = (f & 7) * (nwg >> 3) + (f >> 3);
    const int bx = rr % nx, by = rr / nx;
    const int tid = threadIdx.x;
    const int lane = tid & 63, w = tid >> 6;
    const int m0 = by * 128, n0 = bx * 128;
    // staging: chunk = 16B (8 bf16). chunk p: row r=p>>2, stored col = c ^ (r&3)
    const int r0 = tid >> 2;
    const int c0 = (tid & 3) ^ (r0 & 3);
    const ushort_t* Ag0 = A  + (size_t)(m0 + r0) * lda + c0 * 8;
    const ushort_t* Ag1 = Ag0 + (size_t)64 * lda;
    const ushort_t* Bg0 = Bt + (size_t)(n0 + r0) * ldb + c0 * 8;
    const ushort_t* Bg1 = Bg0 + (size_t)64 * ldb;
    char* AsW = (char*)As + w * 1024;   // wave-uniform LDS dest
    char* BsW = (char*)Bs + w * 1024;
    const int wm = (w & 1) * 64, wn = (w >> 1) * 64;
    const int fn = lane & 15, q = lane >> 4;
    int aoff[4], boff[4];
    #pragma unroll
    for (int i = 0; i < 4; i++) {
        int ra = wm + i * 16 + fn;
        aoff[i] = (ra * 4 + (q ^ (ra & 3))) * 16;
        int rb = wn + i * 16 + fn;
        boff[i] = (rb * 4 + (q ^ (rb & 3))) * 16;
    }
    f32x4 acc[4][4] = {};
    for (int k0 = 0; k0 < K; k0 += 32) {
        gld16(Ag0 + k0, AsW);
        gld16(Ag1 + k0, AsW + 4096);
        gld16(Bg0 + k0, BsW);
        gld16(Bg1 + k0, BsW + 4096);
        __syncthreads();
        s16x8 af[4], bfr[4];
        #pragma unroll
        for (int i = 0; i < 4; i++) {
            af[i]  = *(const s16x8*)((const char*)As + aoff[i]);
            bfr[i] = *(const s16x8*)((const char*)Bs + boff[i]);
        }
        #pragma unroll
        for (int mi = 0; mi < 4; mi++)
            #pragma unroll
            for (int ni = 0; ni < 4; ni++)
                acc[mi][ni] = __builtin_amdgcn_mfma_f32_16x16x32_bf16(
                    af[mi], bfr[ni], acc[mi][ni], 0, 0, 0);
        __syncthreads();
    }
    #pragma unroll
    for (int mi = 0; mi < 4; mi++) {
        #pragma unroll
        for (int ni = 0; ni < 4; ni++) {
            #pragma unroll
            for (int r = 0; r < 4; r++) {
                int gm = m0 + wm + mi * 16 + q * 4 + r;   // C/D row = quad*4+reg
                int gn = n0 + wn + ni * 16 + fn;          // C/D col = lane&15
                float v = acc[mi][ni][r] * scale;
                if (bias) v += bias[gn];
                if (flags & 1) v = 0.5f * v * (1.0f + erff(v * 0.70710678118654752f));
                if (res) v += res[(size_t)gm * ldc + gn];
                if (flags & 2) Cb[(size_t)gm * ldc + gn] = f2bf(v);
                else           Cf[(size_t)gm * ldc + gn] = v;
            }
        }
    }
}

// Fused attention: per block = one (b,h) pair p and a 32-row Q-tile.
// 8 waves; wave w owns S cols [w*128, w*128+128).
// Phase 1: S = (Q @ K^T)/8 in accumulators; block-wide row softmax via
//   shuffle + LDS; write normalized P (fp32, nontemporal) to attn output.
// Phase 2: E (unnormalized exp, bf16) routed through a per-wave XOR-swizzled
//   LDS transpose buffer (two 64-col halves, 4 KB/wave); ctx_partial =
//   (E @ V) * inv; cross-wave reduce in LDS (overlays E buffer); write ctx.
// XCD-aware bijective block swizzle: each XCD owns 8 consecutive p values so
//   K/V (256 KB per p) stay resident in its private L2.
__global__ __launch_bounds__(512) void fused_attn(
    const ushort_t* __restrict__ qh, const ushort_t* __restrict__ kh,
    const ushort_t* __restrict__ vhT, float* __restrict__ attn,
    ushort_t* __restrict__ ctx)
{
    __shared__ __align__(16) char PlBuf[8 * 4096];   // 32 KB: per-wave E tiles / cred overlay
    __shared__ float redm[8][32];
    __shared__ float reds[8][32];
    // bijective XCD swizzle: orig p-major flat id -> XCD-contiguous
    const int orig = blockIdx.y * 32 + blockIdx.x;   // grid (32, 64), 2048 blocks
    const int nf = (orig & 7) * 256 + (orig >> 3);
    const int p = nf >> 5, b = p & 3, h = p >> 2;
    const int m0 = (nf & 31) * 32;
    const int tid = threadIdx.x;
    const int lane = tid & 63, w = tid >> 6;
    const int fn = lane & 15, q = lane >> 4;
    const ushort_t* Qb = qh + (size_t)b * (kL * kD) + h * 64;
    const ushort_t* Kb = kh + (size_t)b * (kL * kD) + h * 64;
    float* Pp = attn + (size_t)p * kL * kL;

    // ---- Phase 1: S = Q K^T * 1/8 ----
    f32x4 acc[2][8] = {};
    #pragma unroll
    for (int kk = 0; kk < 2; kk++) {
        s16x8 aq[2], bq[8];
        #pragma unroll
        for (int mi = 0; mi < 2; mi++)
            aq[mi] = *(const s16x8*)(Qb + (size_t)(m0 + mi * 16 + fn) * kD + kk * 32 + q * 8);
        #pragma unroll
        for (int ni = 0; ni < 8; ni++)
            bq[ni] = *(const s16x8*)(Kb + (size_t)(w * 128 + ni * 16 + fn) * kD + kk * 32 + q * 8);
        #pragma unroll
        for (int mi = 0; mi < 2; mi++)
            #pragma unroll
            for (int ni = 0; ni < 8; ni++)
                acc[mi][ni] = __builtin_amdgcn_mfma_f32_16x16x32_bf16(
                    aq[mi], bq[ni], acc[mi][ni], 0, 0, 0);
    }

    // ---- softmax: scale, wave-local row max over 128 cols ----
    float mloc[2][4];
    #pragma unroll
    for (int mi = 0; mi < 2; mi++) {
        #pragma unroll
        for (int r = 0; r < 4; r++) {
            float m = -3.0e38f;
            #pragma unroll
            for (int ni = 0; ni < 8; ni++) {
                acc[mi][ni][r] *= 0.125f;
                m = fmaxf(m, acc[mi][ni][r]);
            }
            mloc[mi][r] = m;
        }
    }
    #pragma unroll
    for (int o = 1; o < 16; o <<= 1) {
        #pragma unroll
        for (int mi = 0; mi < 2; mi++)
            #pragma unroll
            for (int r = 0; r < 4; r++)
                mloc[mi][r] = fmaxf(mloc[mi][r], __shfl_xor(mloc[mi][r], o, 64));
    }
    if (fn == 0) {
        #pragma unroll
        for (int mi = 0; mi < 2; mi++)
            #pragma unroll
            for (int r = 0; r < 4; r++)
                redm[w][mi * 16 + q * 4 + r] = mloc[mi][r];
    }
    __syncthreads();
    // block row max -> exp -> wave-local row sum
    #pragma unroll
    for (int mi = 0; mi < 2; mi++) {
        #pragma unroll
        for (int r = 0; r < 4; r++) {
            int row = mi * 16 + q * 4 + r;
            float m = redm[0][row];
            #pragma unroll
            for (int w2 = 1; w2 < 8; w2++) m = fmaxf(m, redm[w2][row]);
            float s = 0.f;
            #pragma unroll
            for (int ni = 0; ni < 8; ni++) {
                float e = __expf(acc[mi][ni][r] - m);
                acc[mi][ni][r] = e;
                s += e;
            }
            mloc[mi][r] = s;
        }
    }
    #pragma unroll
    for (int o = 1; o < 16; o <<= 1) {
        #pragma unroll
        for (int mi = 0; mi < 2; mi++)
            #pragma unroll
            for (int r = 0; r < 4; r++)
                mloc[mi][r] += __shfl_xor(mloc[mi][r], o, 64);
    }
    if (fn == 0) {
        #pragma unroll
        for (int mi = 0; mi < 2; mi++)
            #pragma unroll
            for (int r = 0; r < 4; r++)
                reds[w][mi * 16 + q * 4 + r] = mloc[mi][r];
    }
    __syncthreads();
    float inv[2][4];
    #pragma unroll
    for (int mi = 0; mi < 2; mi++) {
        #pragma unroll
        for (int r = 0; r < 4; r++) {
            int row = mi * 16 + q * 4 + r;
            float s = reds[0][row];
            #pragma unroll
            for (int w2 = 1; w2 < 8; w2++) s += reds[w2][row];
            inv[mi][r] = 1.0f / s;
        }
    }
    // ---- write normalized P (required output), nontemporal: never re-read ----
    #pragma unroll
    for (int mi = 0; mi < 2; mi++)
        #pragma unroll
        for (int ni = 0; ni < 8; ni++)
            #pragma unroll
            for (int r = 0; r < 4; r++)
                __builtin_nontemporal_store(
                    acc[mi][ni][r] * inv[mi][r],
                    &Pp[(size_t)(m0 + mi * 16 + q * 4 + r) * kL + w * 128 + ni * 16 + fn]);

    // ---- Phase 2: ctx_partial = (E @ V) * inv via per-wave LDS transpose ----
    // E tile 32x128 bf16 handled in two 64-col halves (4 KB/wave window).
    // LDS layout per half: byte(row, cl) = (row*128 + cl*2) ^ ((row&7)<<4).
    const ushort_t* Vb = vhT + (size_t)p * (kDK * kL);
    char* Plw = PlBuf + w * 4096;
    f32x4 acc2[2][4] = {};
    #pragma unroll
    for (int half = 0; half < 2; half++) {
        #pragma unroll
        for (int mi = 0; mi < 2; mi++)
            #pragma unroll
            for (int ni = 0; ni < 4; ni++)
                #pragma unroll
                for (int r = 0; r < 4; r++) {
                    int row = mi * 16 + q * 4 + r;
                    int cl  = ni * 16 + fn;
                    *(ushort_t*)(Plw + ((row * 128 + cl * 2) ^ ((row & 7) << 4)))
                        = f2bf(acc[mi][half * 4 + ni][r]);
                }
        // per-wave data: DS ops from one wave complete in order; no barrier needed
        #pragma unroll
        for (int kh2 = 0; kh2 < 2; kh2++) {
            int kk = half * 2 + kh2;
            s16x8 pa[2];
            #pragma unroll
            for (int mi = 0; mi < 2; mi++) {
                int row = mi * 16 + fn;
                pa[mi] = *(const s16x8*)(Plw +
                    ((row * 128 + (kh2 * 32 + q * 8) * 2) ^ ((row & 7) << 4)));
            }
            #pragma unroll
            for (int nj = 0; nj < 4; nj++) {
                s16x8 bv = *(const s16x8*)(Vb + (size_t)(nj * 16 + fn) * kL +
                                           w * 128 + kk * 32 + q * 8);
                #pragma unroll
                for (int mi = 0; mi < 2; mi++)
                    acc2[mi][nj] = __builtin_amdgcn_mfma_f32_16x16x32_bf16(
                        pa[mi], bv, acc2[mi][nj], 0, 0, 0);
            }
        }
    }
    // normalize: ctx = diag(inv) * (E @ V)
    #pragma unroll
    for (int mi = 0; mi < 2; mi++)
        #pragma unroll
        for (int nj = 0; nj < 4; nj++)
            #pragma unroll
            for (int r = 0; r < 4; r++)
                acc2[mi][nj][r] *= inv[mi][r];

    // ---- cross-wave reduce (8 -> 4 -> 1); cred overlays PlBuf ----
    __syncthreads();   // all waves done reading their E tiles
    float (*cred)[2048] = (float (*)[2048])PlBuf;   // 4 x 8 KB = 32 KB
    if (w < 4) {
        #pragma unroll
        for (int mi = 0; mi < 2; mi++)
            #pragma unroll
            for (int nj = 0; nj < 4; nj++)
                #pragma unroll
                for (int r = 0; r < 4; r++)
                    cred[w][(mi * 16 + q * 4 + r) * 64 + nj * 16 + fn] = acc2[mi][nj][r];
    }
    __syncthreads();
    if (w >= 4) {
        #pragma unroll
        for (int mi = 0; mi < 2; mi++)
            #pragma unroll
            for (int nj = 0; nj < 4; nj++)
                #pragma unroll
                for (int r = 0; r < 4; r++)
                    cred[w - 4][(mi * 16 + q * 4 + r) * 64 + nj * 16 + fn] += acc2[mi][nj][r];
    }
    __syncthreads();
    {
        int idx0 = tid * 4;                 // 512 thr * 4 = 2048 = 32x64
        int row = idx0 >> 6, d0 = idx0 & 63;
        f32x4 s0 = *(const f32x4*)&cred[0][idx0];
        #pragma unroll
        for (int wb = 1; wb < 4; wb++) {
            f32x4 t = *(const f32x4*)&cred[wb][idx0];
            s0[0] += t[0]; s0[1] += t[1]; s0[2] += t[2]; s0[3] += t[3];
        }
        u16x4 o;
        o[0] = f2bf(s0[0]); o[1] = f2bf(s0[1]); o[2] = f2bf(s0[2]); o[3] = f2bf(s0[3]);
        *(u16x4*)(ctx + (size_t)b * (kL * kD) + (size_t)(m0 + row) * kD + h * 64 + d0) = o;
    }
}

} // namespace

extern "C" void kernel_launch(void* const* d_in, const int* in_sizes, int n_in,
                              void* d_out, int out_size, void* d_ws, size_t ws_size,
                              hipStream_t stream)
{
    (void)in_sizes; (void)n_in; (void)out_size; (void)ws_size;
    const float* q      = (const float*)d_in[0];
    const float* k      = (const float*)d_in[1];
    const float* v      = (const float*)d_in[2];
    const float* z      = (const float*)d_in[3];
    const float* wq_w   = (const float*)d_in[4];
    const float* wq_b   = (const float*)d_in[5];
    const float* wk_w   = (const float*)d_in[6];
    const float* wk_b   = (const float*)d_in[7];
    const float* wv_w   = (const float*)d_in[8];
    const float* wv_b   = (const float*)d_in[9];
    const float* fc_w   = (const float*)d_in[10];
    const float* fc_b   = (const float*)d_in[11];
    const float* mlp1_w = (const float*)d_in[12];
    const float* mlp1_b = (const float*)d_in[13];
    const float* mlp2_w = (const float*)d_in[14];
    const float* mlp2_b = (const float*)d_in[15];
    const float* ln1_w  = (const float*)d_in[16];
    const float* ln1_b  = (const float*)d_in[17];
    const float* g1     = (const float*)d_in[18];
    const float* b1     = (const float*)d_in[19];
    const float* ln2_w  = (const float*)d_in[20];
    const float* ln2_b  = (const float*)d_in[21];
    const float* g2     = (const float*)d_in[22];
    const float* b2     = (const float*)d_in[23];

    float* out0 = (float*)d_out;                          // (B,L,D)
    float* attn = (float*)d_out + (size_t)kB * kL * kD;   // (H*B,L,L)

    // workspace arena (104 MB peak, lifetime-overlay layout)
    //  [0,16)   qp (fp32)       -> dead after fc;   hid (bf16, 32MB) = [0,32) at mlp1
    //  [16,24)  qb  [24,32) kb  -> dead after QKV;  fcP (fp32 16MB) = [16,32) at fc
    //  [32,40)  vb -> vhT after vtrans -> h2 (bf16) after fused_attn
    //  [40,48)  qh  [48,56) kh  -> dead after fused_attn; m2P (fp32 16MB) = [40,56)
    //  [56,64)  vh -> ctx after fused_attn
    //  [64,80)  out1 (fp32)
    //  [80,104) weights: wqT,wkT,wvT,fcT (2MB each), m1T [88,96), m2T [96,104)
    char* arena = (char*)d_ws;
    const size_t MB = 1u << 20;
    float*    qp   = (float*)(arena);
    ushort_t* qb   = (ushort_t*)(arena + 16 * MB);
    ushort_t* kb   = (ushort_t*)(arena + 24 * MB);
    ushort_t* vb   = (ushort_t*)(arena + 32 * MB);
    ushort_t* qh   = (ushort_t*)(arena + 40 * MB);
    ushort_t* kh   = (ushort_t*)(arena + 48 * MB);
    ushort_t* vh   = (ushort_t*)(arena + 56 * MB);
    ushort_t* vhT  = (ushort_t*)(arena + 32 * MB);     // overlays vb (dead)
    ushort_t* ctx  = (ushort_t*)(arena + 56 * MB);     // overlays vh (dead)
    float*    fcP  = (float*)(arena + 16 * MB);        // overlays qb,kb (dead)
    ushort_t* h2   = (ushort_t*)(arena + 32 * MB);     // overlays vhT (dead)
    float*    out1 = (float*)(arena + 64 * MB);
    ushort_t* hid  = (ushort_t*)(arena);               // [0,32) overlays qp,fcP (dead)
    float*    m2P  = (float*)(arena + 40 * MB);        // overlays qh,kh (dead)
    ushort_t* wqT  = (ushort_t*)(arena + 80 * MB);
    ushort_t* fcT  = (ushort_t*)(arena + 86 * MB);
    ushort_t* m1T  = (ushort_t*)(arena + 88 * MB);
    ushort_t* m2T  = (ushort_t*)(arena + 96 * MB);

    dim3 blk(256);
    // 0) weight transpose+convert: four 1024x1024 in one launch, then mlp1/mlp2
    twcvt4<<<dim3(32, 32, 4), blk, 0, stream>>>(wq_w, wk_w, wv_w, fc_w, wqT);
    twcvt<<<dim3(128, 32), blk, 0, stream>>>(mlp1_w, m1T, kD, kHID);
    twcvt<<<dim3(32, 128), blk, 0, stream>>>(mlp2_w, m2T, kHID, kD);
    // 0b) k, v -> bf16 (one launch; kb,vb contiguous)
    cvt2_bf16<<<dim3(8192), blk, 0, stream>>>(k, v, kb);
    // 1) q' = SLN(q, z): fp32 (residual) + bf16 (GEMM input)
    sln_kernel<<<dim3(kB * kL), blk, 0, stream>>>(q, nullptr, nullptr, z,
                                                  ln1_w, ln1_b, g1, b1, qp, qb);
    // 2) QKV projections -> bf16 heads, one batched launch (768 blocks = 3/CU)
    mgemm<<<dim3(8, 32, 3), blk, 0, stream>>>(qb, kD, wqT, kD, qh, kD, kD,
                                              wq_b, nullptr, 1.0f, 2, 2, wk_b, wv_b, nullptr);
    // 3) V^T per head
    vtrans<<<dim3(32, 2, 64), blk, 0, stream>>>(vh, vhT);
    // 4) fused scores+softmax+PV: attn (fp32, d_out) and ctx (bf16)
    fused_attn<<<dim3(kL / 32, 64), dim3(512), 0, stream>>>(qh, kh, vhT, attn, ctx);
    // 5) out1 = ctx @ fc_w + fc_b + q', split-K x2 (512 blocks = 2/CU):
    //    z=0 -> out1 (K 0..511, bias+res), z=1 -> fcP raw partial (K 512..1023)
    mgemm<<<dim3(8, 32, 2), blk, 0, stream>>>(ctx, kD, fcT, kD, out1, kD, kD / 2,
                                              fc_b, qp, 1.0f, 0, 3, nullptr, nullptr, fcP);
    // 6) h2 = SLN(out1 + fcP, z) -> bf16; writes fixed out1 back (residual for 8)
    sln_kernel<<<dim3(kB * kL), blk, 0, stream>>>(out1, fcP, out1, z,
                                                  ln2_w, ln2_b, g2, b2, nullptr, h2);
    // 7) hid = gelu(h2 @ mlp1 + b) -> bf16 (1024 blocks = 4/CU)
    mgemm<<<dim3(32, 32, 1), blk, 0, stream>>>(h2, kD, m1T, kD, hid, kHID, kD,
                                               mlp1_b, nullptr, 1.0f, 3, 0, nullptr, nullptr, nullptr);
    // 8) out0 = hid @ mlp2 + b + out1, split-K x2 (512 blocks = 2/CU):
    //    z=0 -> out0 (K 0..2047, bias+res), z=1 -> m2P raw partial
    mgemm<<<dim3(8, 32, 2), blk, 0, stream>>>(hid, kHID, m2T, kHID, out0, kD, kHID / 2,
                                              mlp2_b, out1, 1.0f, 0, 3, nullptr, nullptr, m2P);
    // 9) out0 += m2P
    addf4<<<dim3(4096), blk, 0, stream>>>(out0, m2P);
}